// Round 6
// baseline (636.280 us; speedup 1.0000x reference)
//
#include <hip/hip_runtime.h>
#include <math.h>

#define MIN_NORM 1e-15f
#define MAXN     0.996f          // (1 - 4e-3)/sqrt(c), c=1
#define ATC      0.9999999f      // artanh clip = 1 - 1e-7

typedef _Float16 f16x8 __attribute__((ext_vector_type(8)));

__device__ __forceinline__ float fast_artanh(float v) {
    v = fminf(fmaxf(v, -ATC), ATC);
    return 0.5f * __logf((1.0f + v) / (1.0f - v));
}
__device__ __forceinline__ float fast_tanh(float xv) {
    float e2 = __expf(2.0f * xv);
    return (e2 - 1.0f) / (e2 + 1.0f);
}
__device__ __forceinline__ float reduce16(float v) {
    v += __shfl_xor(v, 1);
    v += __shfl_xor(v, 2);
    v += __shfl_xor(v, 4);
    v += __shfl_xor(v, 8);
    return v;
}

// ---- kernel 1: fused HypLinear + logmap0. One wave per row-GEMM, x in
// registers; W tile packed fp16 (64 VGPR) -> 4 waves/SIMD for latency hiding.
// Möbius tail batched 4 rows/wave. Writes xt as fp16. ----
__global__ __launch_bounds__(256, 4) void hgcn_k1(
    const float* __restrict__ x, const float* __restrict__ weight,
    const float* __restrict__ bias, _Float16* __restrict__ xt, int N)
{
    const int tid  = threadIdx.x;
    const int lane = tid & 63;
    const int wib  = tid >> 6;           // wave in block (0..3)
    const int k    = lane & 15;
    const int grp  = lane >> 4;          // 16-lane group (0..3)

    // W fragment in packed fp16 registers: wrh[kk][jj] = W[kk][lane*8 + jj]
    f16x8 wrh[16];
    const float* wp = weight + lane * 8;
#pragma unroll
    for (int kk = 0; kk < 16; ++kk) {
        float4 a = *(const float4*)(wp + kk * 512);
        float4 b = *(const float4*)(wp + kk * 512 + 4);
        f16x8 h;
        h[0] = (_Float16)a.x; h[1] = (_Float16)a.y;
        h[2] = (_Float16)a.z; h[3] = (_Float16)a.w;
        h[4] = (_Float16)b.x; h[5] = (_Float16)b.y;
        h[6] = (_Float16)b.z; h[7] = (_Float16)b.w;
        wrh[kk] = h;
    }

    // hyp_bias = proj(expmap0(bias)) — replicated per 16-lane group
    float bb = bias[k];
    float b2 = reduce16(bb * bb);
    float bn = fmaxf(sqrtf(b2), MIN_NORM);
    float eb = fast_tanh(bn) * bb / bn;
    float e2 = reduce16(eb * eb);
    float en = fmaxf(sqrtf(e2), MIN_NORM);
    float hb = (en > MAXN) ? eb * (MAXN / en) : eb;
    float y2 = reduce16(hb * hb);

    const long long stride = (long long)gridDim.x * 4 * 4;   // rows per sweep
    long long base = ((long long)blockIdx.x * 4 + wib) * 4;  // 4 rows per wave

    float4 c0 = {0,0,0,0}, c1 = {0,0,0,0};
    if (base < N) {
        const float* xr = x + base * 512 + lane * 8;
        c0 = *(const float4*)(xr);
        c1 = *(const float4*)(xr + 4);
    }

    while (base < N) {
        float x2sel = 0.0f, mxsel = 0.0f;

#pragma unroll
        for (int p = 0; p < 4; ++p) {
            long long nrow = (p < 3) ? (base + p + 1) : (base + stride);
            float4 n0 = {0,0,0,0}, n1 = {0,0,0,0};
            if (nrow < N) {              // prefetch next row
                const float* xr = x + nrow * 512 + lane * 8;
                n0 = *(const float4*)(xr);
                n1 = *(const float4*)(xr + 4);
            }

            float xv[8] = {c0.x, c0.y, c0.z, c0.w, c1.x, c1.y, c1.z, c1.w};

            // ||x||^2 over all 64 lanes
            float pq = 0.0f;
#pragma unroll
            for (int jj = 0; jj < 8; ++jj) pq = fmaf(xv[jj], xv[jj], pq);
#pragma unroll
            for (int m = 1; m <= 32; m <<= 1) pq += __shfl_xor(pq, m);
            if (grp == p) x2sel = pq;

            // GEMM + value-halving butterfly (stage 1 fused with the FMAs)
            float v8[8];
            {
                const bool h = lane & 1;
#pragma unroll
                for (int i = 0; i < 8; ++i) {
                    float a0 = 0.0f, a1 = 0.0f;
#pragma unroll
                    for (int jj = 0; jj < 8; ++jj) {
                        a0 = fmaf((float)wrh[2*i][jj],   xv[jj], a0);
                        a1 = fmaf((float)wrh[2*i+1][jj], xv[jj], a1);
                    }
                    float keep = h ? a1 : a0;
                    float give = h ? a0 : a1;
                    v8[i] = keep + __shfl_xor(give, 1);
                }
            }
            float v4[4];
            {
                const bool h = lane & 2;
#pragma unroll
                for (int i = 0; i < 4; ++i) {
                    float keep = h ? v8[2*i+1] : v8[2*i];
                    float give = h ? v8[2*i]   : v8[2*i+1];
                    v4[i] = keep + __shfl_xor(give, 2);
                }
            }
            float v2[2];
            {
                const bool h = lane & 4;
#pragma unroll
                for (int i = 0; i < 2; ++i) {
                    float keep = h ? v4[2*i+1] : v4[2*i];
                    float give = h ? v4[2*i]   : v4[2*i+1];
                    v2[i] = keep + __shfl_xor(give, 4);
                }
            }
            float mx;
            {
                const bool h = lane & 8;
                float keep = h ? v2[1] : v2[0];
                float give = h ? v2[0] : v2[1];
                mx = keep + __shfl_xor(give, 8);
            }
            mx += __shfl_xor(mx, 16);
            mx += __shfl_xor(mx, 32);
            if (grp == p) mxsel = mx;

            c0 = n0; c1 = n1;
        }

        // ---- Möbius tail: each 16-lane group handles row (base+grp) ----
        float mx2 = reduce16(mxsel * mxsel);
        float xn  = fmaxf(sqrtf(x2sel), MIN_NORM);
        float mxn = fmaxf(sqrtf(mx2),   MIN_NORM);
        float res = fast_tanh(mxn / xn * fast_artanh(xn)) * mxsel / mxn;
        if (mx2 == 0.0f) res = 0.0f;
        // proj
        float rn2 = reduce16(res * res);
        float rn  = fmaxf(sqrtf(rn2), MIN_NORM);
        float mv  = (rn > MAXN) ? res * (MAXN / rn) : res;
        // mobius_add(mv, hyp_bias)
        float mv2 = reduce16(mv * mv);
        float xy  = reduce16(mv * hb);
        float num = (1.0f + 2.0f * xy + y2) * mv + (1.0f - mv2) * hb;
        float den = 1.0f + 2.0f * xy + mv2 * y2;
        float hq  = num / fmaxf(den, MIN_NORM);
        // proj
        float hn2 = reduce16(hq * hq);
        float hn  = fmaxf(sqrtf(hn2), MIN_NORM);
        float hp  = (hn > MAXN) ? hq * (MAXN / hn) : hq;
        // logmap0
        float hp2 = reduce16(hp * hp);
        float pn  = fmaxf(sqrtf(hp2), MIN_NORM);
        float xtv = fast_artanh(pn) * hp / pn;

        long long myrow = base + grp;
        if (myrow < N) xt[myrow * 16 + k] = (_Float16)xtv;  // 32B/group

        base += stride;
    }
}

// ---------------- index width detection ----------------
__global__ void hgcn_k_detect(const void* srcp, long long E, int* flag)
{
    const int tid = threadIdx.x;
    if (tid == 0) *flag = 0;
    __syncthreads();
    long long n = E / 2; if (n > 4096) n = 4096;
    int bad = 0;
    const unsigned long long* p = (const unsigned long long*)srcp;
    for (long long i = tid; i < n; i += 256)
        if (p[i] >= (1ULL << 32)) bad = 1;
    if (bad) atomicOr(flag, 1);
}

// ---- kernel 2: edge scatter-add, 16 lanes/edge, persistent + 2-stage pipe ---
// 16 consecutive lanes hit one 64B-aligned destination line -> TCC line-merge.
// Index/weight streams use non-temporal loads so L2 keeps fp16 xt resident.
__global__ __launch_bounds__(256) void hgcn_k2(
    const void* __restrict__ srcp, const void* __restrict__ dstp,
    const float* __restrict__ ew, const _Float16* __restrict__ xt,
    float* __restrict__ agg, long long E, const int* __restrict__ flag)
{
    const int k = threadIdx.x & 15;
    const bool i32 = (*flag != 0);
    const long long slots = ((long long)gridDim.x * 256) >> 4;
    long long e = ((long long)blockIdx.x * 256 + threadIdx.x) >> 4;

    long long d0 = 0; float w0 = 0.0f, v0 = 0.0f;
    bool have = e < E;
    if (have) {
        long long s0;
        if (i32) { s0 = __builtin_nontemporal_load((const int*)srcp + e);
                   d0 = __builtin_nontemporal_load((const int*)dstp + e); }
        else     { s0 = __builtin_nontemporal_load((const long long*)srcp + e);
                   d0 = __builtin_nontemporal_load((const long long*)dstp + e); }
        w0 = __builtin_nontemporal_load(ew + e);
        v0 = (float)xt[s0 * 16 + k];
    }
    while (have) {
        long long en = e + slots;
        long long d1 = 0; float w1 = 0.0f, v1 = 0.0f;
        bool haven = en < E;
        if (haven) {                      // prefetch next edge
            long long s1;
            if (i32) { s1 = __builtin_nontemporal_load((const int*)srcp + en);
                       d1 = __builtin_nontemporal_load((const int*)dstp + en); }
            else     { s1 = __builtin_nontemporal_load((const long long*)srcp + en);
                       d1 = __builtin_nontemporal_load((const long long*)dstp + en); }
            w1 = __builtin_nontemporal_load(ew + en);
            v1 = (float)xt[s1 * 16 + k];
        }
        atomicAdd(&agg[d0 * 16 + k], w0 * v0);
        e = en; d0 = d1; w0 = w1; v0 = v1; have = haven;
    }
}

// ---------------- kernel 3: finalize in place on d_out -----------------------
__global__ __launch_bounds__(256) void hgcn_k3(float* __restrict__ out, int N)
{
    int gid = blockIdx.x * blockDim.x + threadIdx.x;
    int row = gid >> 4;
    if (row >= N) return;
    float u = out[(size_t)row * 16 + (gid & 15)];

    float un2 = reduce16(u * u);
    float un  = fmaxf(sqrtf(un2), MIN_NORM);
    float h1  = fast_tanh(un) * u / un;
    float n2  = reduce16(h1 * h1);
    float n1  = fmaxf(sqrtf(n2), MIN_NORM);
    float h1p = (n1 > MAXN) ? h1 * (MAXN / n1) : h1;
    float m2  = reduce16(h1p * h1p);
    float pn  = fmaxf(sqrtf(m2), MIN_NORM);
    float xt2 = fast_artanh(pn) * h1p / pn;
    float a2  = reduce16(xt2 * xt2);
    float an  = fmaxf(sqrtf(a2), MIN_NORM);
    float h2  = fast_tanh(an) * xt2 / an;
    float b2  = reduce16(h2 * h2);
    float bn  = fmaxf(sqrtf(b2), MIN_NORM);
    float h2p = (bn > MAXN) ? h2 * (MAXN / bn) : h2;
    float c2  = reduce16(h2p * h2p);
    float cn  = fmaxf(sqrtf(c2), MIN_NORM);
    out[(size_t)row * 16 + (gid & 15)] = fast_artanh(cn) * h2p / cn;
}

extern "C" void kernel_launch(void* const* d_in, const int* in_sizes, int n_in,
                              void* d_out, int out_size, void* d_ws, size_t ws_size,
                              hipStream_t stream)
{
    const float* x        = (const float*)d_in[0];
    const float* weight   = (const float*)d_in[1];
    const float* bias     = (const float*)d_in[2];
    const float* edge_w   = (const float*)d_in[3];
    const void*  edge_src = d_in[4];
    const void*  edge_dst = d_in[5];

    const int Kv = in_sizes[2];          // 16
    const int Dv = in_sizes[1] / Kv;     // 512
    const int N  = in_sizes[0] / Dv;     // 100000
    const long long E = in_sizes[3];     // 3200000

    int*      flag = (int*)d_ws;
    _Float16* xt   = (_Float16*)((char*)d_ws + 256);
    float*    agg  = (float*)d_out;

    hipMemsetAsync(d_out, 0, (size_t)N * 16 * sizeof(float), stream);
    hipLaunchKernelGGL(hgcn_k_detect, dim3(1), dim3(256), 0, stream, edge_src, E, flag);
    hipLaunchKernelGGL(hgcn_k1, dim3(1024), dim3(256), 0, stream,
                       x, weight, bias, xt, N);
    hipLaunchKernelGGL(hgcn_k2, dim3(2048), dim3(256), 0, stream,
                       edge_src, edge_dst, edge_w, xt, agg, E, flag);
    hipLaunchKernelGGL(hgcn_k3, dim3((unsigned)(((long long)N * 16 + 255) / 256)), dim3(256), 0, stream,
                       agg, N);
}

// Round 7
// 263.741 us; speedup vs baseline: 2.4125x; 2.4125x over previous
//
#include <hip/hip_runtime.h>
#include <math.h>

#define MIN_NORM 1e-15f
#define MAXN     0.996f          // (1 - 4e-3)/sqrt(c), c=1
#define ATC      0.9999999f      // artanh clip = 1 - 1e-7

__device__ __forceinline__ float fast_artanh(float v) {
    v = fminf(fmaxf(v, -ATC), ATC);
    return 0.5f * __logf((1.0f + v) / (1.0f - v));
}
__device__ __forceinline__ float fast_tanh(float xv) {
    float e2 = __expf(2.0f * xv);
    return (e2 - 1.0f) / (e2 + 1.0f);
}
__device__ __forceinline__ float reduce16(float v) {
    v += __shfl_xor(v, 1);
    v += __shfl_xor(v, 2);
    v += __shfl_xor(v, 4);
    v += __shfl_xor(v, 8);
    return v;
}

// ---- kernel 1: fused HypLinear + logmap0. One wave per row-GEMM, x in
// registers (fp32 W tile: 128 VGPR — do NOT force occupancy, spills are
// catastrophic, see round-6). 2-row-deep prefetch hides HBM latency at
// 2 waves/SIMD. Möbius tail batched 4 rows/wave. Writes xt as fp16. ----
__global__ __launch_bounds__(256) void hgcn_k1(
    const float* __restrict__ x, const float* __restrict__ weight,
    const float* __restrict__ bias, _Float16* __restrict__ xt, int N)
{
    const int tid  = threadIdx.x;
    const int lane = tid & 63;
    const int wib  = tid >> 6;           // wave in block (0..3)
    const int k    = lane & 15;
    const int grp  = lane >> 4;          // 16-lane group (0..3)

    // W fragment in registers: wr[kk][jj] = W[kk][lane*8 + jj]
    float wr[16][8];
    const float* wp = weight + lane * 8;
#pragma unroll
    for (int kk = 0; kk < 16; ++kk) {
        float4 a = *(const float4*)(wp + kk * 512);
        float4 b = *(const float4*)(wp + kk * 512 + 4);
        wr[kk][0] = a.x; wr[kk][1] = a.y; wr[kk][2] = a.z; wr[kk][3] = a.w;
        wr[kk][4] = b.x; wr[kk][5] = b.y; wr[kk][6] = b.z; wr[kk][7] = b.w;
    }

    // hyp_bias = proj(expmap0(bias)) — replicated per 16-lane group
    float bb = bias[k];
    float b2 = reduce16(bb * bb);
    float bn = fmaxf(sqrtf(b2), MIN_NORM);
    float eb = fast_tanh(bn) * bb / bn;
    float e2 = reduce16(eb * eb);
    float en = fmaxf(sqrtf(e2), MIN_NORM);
    float hb = (en > MAXN) ? eb * (MAXN / en) : eb;
    float y2 = reduce16(hb * hb);

    const long long stride = (long long)gridDim.x * 16;      // rows per sweep
    long long base = ((long long)blockIdx.x * 4 + wib) * 4;  // 4 rows per wave

    // 2-deep prefetch pipeline: c = row base+p, n = row base+p+1 in flight
    float4 c0 = {0,0,0,0}, c1 = {0,0,0,0};
    float4 n0 = {0,0,0,0}, n1 = {0,0,0,0};
    if (base < N) {
        const float* xr = x + base * 512 + lane * 8;
        c0 = *(const float4*)(xr);
        c1 = *(const float4*)(xr + 4);
    }
    if (base + 1 < N) {
        const float* xr = x + (base + 1) * 512 + lane * 8;
        n0 = *(const float4*)(xr);
        n1 = *(const float4*)(xr + 4);
    }

    while (base < N) {
        float x2sel = 0.0f, mxsel = 0.0f;

#pragma unroll
        for (int p = 0; p < 4; ++p) {
            // issue load for row base+p+2 (wraps into next sweep)
            long long r2 = (p < 2) ? (base + p + 2) : (base + stride + (p - 2));
            float4 m0 = {0,0,0,0}, m1 = {0,0,0,0};
            if (r2 < N) {
                const float* xr = x + r2 * 512 + lane * 8;
                m0 = *(const float4*)(xr);
                m1 = *(const float4*)(xr + 4);
            }

            float xv[8] = {c0.x, c0.y, c0.z, c0.w, c1.x, c1.y, c1.z, c1.w};

            // ||x||^2 over all 64 lanes
            float pq = 0.0f;
#pragma unroll
            for (int jj = 0; jj < 8; ++jj) pq = fmaf(xv[jj], xv[jj], pq);
#pragma unroll
            for (int m = 1; m <= 32; m <<= 1) pq += __shfl_xor(pq, m);
            if (grp == p) x2sel = pq;

            // GEMM + value-halving butterfly (stage 1 fused with the FMAs)
            float v8[8];
            {
                const bool h = lane & 1;
#pragma unroll
                for (int i = 0; i < 8; ++i) {
                    float a0 = 0.0f, a1 = 0.0f;
#pragma unroll
                    for (int jj = 0; jj < 8; ++jj) {
                        a0 = fmaf(wr[2*i][jj],   xv[jj], a0);
                        a1 = fmaf(wr[2*i+1][jj], xv[jj], a1);
                    }
                    float keep = h ? a1 : a0;
                    float give = h ? a0 : a1;
                    v8[i] = keep + __shfl_xor(give, 1);
                }
            }
            float v4[4];
            {
                const bool h = lane & 2;
#pragma unroll
                for (int i = 0; i < 4; ++i) {
                    float keep = h ? v8[2*i+1] : v8[2*i];
                    float give = h ? v8[2*i]   : v8[2*i+1];
                    v4[i] = keep + __shfl_xor(give, 2);
                }
            }
            float v2[2];
            {
                const bool h = lane & 4;
#pragma unroll
                for (int i = 0; i < 2; ++i) {
                    float keep = h ? v4[2*i+1] : v4[2*i];
                    float give = h ? v4[2*i]   : v4[2*i+1];
                    v2[i] = keep + __shfl_xor(give, 4);
                }
            }
            float mx;
            {
                const bool h = lane & 8;
                float keep = h ? v2[1] : v2[0];
                float give = h ? v2[0] : v2[1];
                mx = keep + __shfl_xor(give, 8);
            }
            mx += __shfl_xor(mx, 16);
            mx += __shfl_xor(mx, 32);
            if (grp == p) mxsel = mx;

            c0 = n0; c1 = n1;          // rotate pipeline
            n0 = m0; n1 = m1;
        }

        // ---- Möbius tail: each 16-lane group handles row (base+grp) ----
        float mx2 = reduce16(mxsel * mxsel);
        float xn  = fmaxf(sqrtf(x2sel), MIN_NORM);
        float mxn = fmaxf(sqrtf(mx2),   MIN_NORM);
        float res = fast_tanh(mxn / xn * fast_artanh(xn)) * mxsel / mxn;
        if (mx2 == 0.0f) res = 0.0f;
        // proj
        float rn2 = reduce16(res * res);
        float rn  = fmaxf(sqrtf(rn2), MIN_NORM);
        float mv  = (rn > MAXN) ? res * (MAXN / rn) : res;
        // mobius_add(mv, hyp_bias)
        float mv2 = reduce16(mv * mv);
        float xy  = reduce16(mv * hb);
        float num = (1.0f + 2.0f * xy + y2) * mv + (1.0f - mv2) * hb;
        float den = 1.0f + 2.0f * xy + mv2 * y2;
        float hq  = num / fmaxf(den, MIN_NORM);
        // proj
        float hn2 = reduce16(hq * hq);
        float hn  = fmaxf(sqrtf(hn2), MIN_NORM);
        float hp  = (hn > MAXN) ? hq * (MAXN / hn) : hq;
        // logmap0
        float hp2 = reduce16(hp * hp);
        float pn  = fmaxf(sqrtf(hp2), MIN_NORM);
        float xtv = fast_artanh(pn) * hp / pn;

        long long myrow = base + grp;
        if (myrow < N) xt[myrow * 16 + k] = (_Float16)xtv;  // 32B/group

        base += stride;
    }
}

// ---------------- index width detection ----------------
__global__ void hgcn_k_detect(const void* srcp, long long E, int* flag)
{
    const int tid = threadIdx.x;
    if (tid == 0) *flag = 0;
    __syncthreads();
    long long n = E / 2; if (n > 4096) n = 4096;
    int bad = 0;
    const unsigned long long* p = (const unsigned long long*)srcp;
    for (long long i = tid; i < n; i += 256)
        if (p[i] >= (1ULL << 32)) bad = 1;
    if (bad) atomicOr(flag, 1);
}

// ---- kernel 2: edge scatter-add, 16 lanes/edge, persistent + 2-stage pipe ---
// 16 consecutive lanes hit one 64B-aligned destination line -> TCC line-merge.
// Index/weight streams use non-temporal loads so L2 keeps fp16 xt resident.
// Floored at 3.2M random 64B atomic-line RMWs (~19 G lines/s), see rounds 4-5.
__global__ __launch_bounds__(256) void hgcn_k2(
    const void* __restrict__ srcp, const void* __restrict__ dstp,
    const float* __restrict__ ew, const _Float16* __restrict__ xt,
    float* __restrict__ agg, long long E, const int* __restrict__ flag)
{
    const int k = threadIdx.x & 15;
    const bool i32 = (*flag != 0);
    const long long slots = ((long long)gridDim.x * 256) >> 4;
    long long e = ((long long)blockIdx.x * 256 + threadIdx.x) >> 4;

    long long d0 = 0; float w0 = 0.0f, v0 = 0.0f;
    bool have = e < E;
    if (have) {
        long long s0;
        if (i32) { s0 = __builtin_nontemporal_load((const int*)srcp + e);
                   d0 = __builtin_nontemporal_load((const int*)dstp + e); }
        else     { s0 = __builtin_nontemporal_load((const long long*)srcp + e);
                   d0 = __builtin_nontemporal_load((const long long*)dstp + e); }
        w0 = __builtin_nontemporal_load(ew + e);
        v0 = (float)xt[s0 * 16 + k];
    }
    while (have) {
        long long en = e + slots;
        long long d1 = 0; float w1 = 0.0f, v1 = 0.0f;
        bool haven = en < E;
        if (haven) {                      // prefetch next edge
            long long s1;
            if (i32) { s1 = __builtin_nontemporal_load((const int*)srcp + en);
                       d1 = __builtin_nontemporal_load((const int*)dstp + en); }
            else     { s1 = __builtin_nontemporal_load((const long long*)srcp + en);
                       d1 = __builtin_nontemporal_load((const long long*)dstp + en); }
            w1 = __builtin_nontemporal_load(ew + en);
            v1 = (float)xt[s1 * 16 + k];
        }
        atomicAdd(&agg[d0 * 16 + k], w0 * v0);
        e = en; d0 = d1; w0 = w1; v0 = v1; have = haven;
    }
}

// ---------------- kernel 3: finalize in place on d_out -----------------------
__global__ __launch_bounds__(256) void hgcn_k3(float* __restrict__ out, int N)
{
    int gid = blockIdx.x * blockDim.x + threadIdx.x;
    int row = gid >> 4;
    if (row >= N) return;
    float u = out[(size_t)row * 16 + (gid & 15)];

    float un2 = reduce16(u * u);
    float un  = fmaxf(sqrtf(un2), MIN_NORM);
    float h1  = fast_tanh(un) * u / un;
    float n2  = reduce16(h1 * h1);
    float n1  = fmaxf(sqrtf(n2), MIN_NORM);
    float h1p = (n1 > MAXN) ? h1 * (MAXN / n1) : h1;
    float m2  = reduce16(h1p * h1p);
    float pn  = fmaxf(sqrtf(m2), MIN_NORM);
    float xt2 = fast_artanh(pn) * h1p / pn;
    float a2  = reduce16(xt2 * xt2);
    float an  = fmaxf(sqrtf(a2), MIN_NORM);
    float h2  = fast_tanh(an) * xt2 / an;
    float b2  = reduce16(h2 * h2);
    float bn  = fmaxf(sqrtf(b2), MIN_NORM);
    float h2p = (bn > MAXN) ? h2 * (MAXN / bn) : h2;
    float c2  = reduce16(h2p * h2p);
    float cn  = fmaxf(sqrtf(c2), MIN_NORM);
    out[(size_t)row * 16 + (gid & 15)] = fast_artanh(cn) * h2p / cn;
}

extern "C" void kernel_launch(void* const* d_in, const int* in_sizes, int n_in,
                              void* d_out, int out_size, void* d_ws, size_t ws_size,
                              hipStream_t stream)
{
    const float* x        = (const float*)d_in[0];
    const float* weight   = (const float*)d_in[1];
    const float* bias     = (const float*)d_in[2];
    const float* edge_w   = (const float*)d_in[3];
    const void*  edge_src = d_in[4];
    const void*  edge_dst = d_in[5];

    const int Kv = in_sizes[2];          // 16
    const int Dv = in_sizes[1] / Kv;     // 512
    const int N  = in_sizes[0] / Dv;     // 100000
    const long long E = in_sizes[3];     // 3200000

    int*      flag = (int*)d_ws;
    _Float16* xt   = (_Float16*)((char*)d_ws + 256);
    float*    agg  = (float*)d_out;

    hipMemsetAsync(d_out, 0, (size_t)N * 16 * sizeof(float), stream);
    hipLaunchKernelGGL(hgcn_k_detect, dim3(1), dim3(256), 0, stream, edge_src, E, flag);
    hipLaunchKernelGGL(hgcn_k1, dim3(1024), dim3(256), 0, stream,
                       x, weight, bias, xt, N);
    hipLaunchKernelGGL(hgcn_k2, dim3(2048), dim3(256), 0, stream,
                       edge_src, edge_dst, edge_w, xt, agg, E, flag);
    hipLaunchKernelGGL(hgcn_k3, dim3((unsigned)(((long long)N * 16 + 255) / 256)), dim3(256), 0, stream,
                       agg, N);
}

// Round 9
// 260.186 us; speedup vs baseline: 2.4455x; 1.0137x over previous
//
#include <hip/hip_runtime.h>
#include <hip/hip_fp16.h>
#include <math.h>

#define MIN_NORM 1e-15f
#define MAXN     0.996f          // (1 - 4e-3)/sqrt(c), c=1
#define ATC      0.9999999f      // artanh clip = 1 - 1e-7

__device__ __forceinline__ float fast_artanh(float v) {
    v = fminf(fmaxf(v, -ATC), ATC);
    return 0.5f * __logf((1.0f + v) / (1.0f - v));
}
__device__ __forceinline__ float fast_tanh(float xv) {
    float e2 = __expf(2.0f * xv);
    return (e2 - 1.0f) / (e2 + 1.0f);
}
__device__ __forceinline__ float reduce16(float v) {
    v += __shfl_xor(v, 1);
    v += __shfl_xor(v, 2);
    v += __shfl_xor(v, 4);
    v += __shfl_xor(v, 8);
    return v;
}

// ---- kernel 1: fused HypLinear + logmap0. One wave per row-GEMM, x in
// registers (fp32 W tile: 128 VGPR — do NOT force occupancy, spills are
// catastrophic, see round-6). Möbius tail batched 4 rows/wave. xt out fp16. --
__global__ __launch_bounds__(256) void hgcn_k1(
    const float* __restrict__ x, const float* __restrict__ weight,
    const float* __restrict__ bias, _Float16* __restrict__ xt, int N)
{
    const int tid  = threadIdx.x;
    const int lane = tid & 63;
    const int wib  = tid >> 6;           // wave in block (0..3)
    const int k    = lane & 15;
    const int grp  = lane >> 4;          // 16-lane group (0..3)

    // W fragment in registers: wr[kk][jj] = W[kk][lane*8 + jj]
    float wr[16][8];
    const float* wp = weight + lane * 8;
#pragma unroll
    for (int kk = 0; kk < 16; ++kk) {
        float4 a = *(const float4*)(wp + kk * 512);
        float4 b = *(const float4*)(wp + kk * 512 + 4);
        wr[kk][0] = a.x; wr[kk][1] = a.y; wr[kk][2] = a.z; wr[kk][3] = a.w;
        wr[kk][4] = b.x; wr[kk][5] = b.y; wr[kk][6] = b.z; wr[kk][7] = b.w;
    }

    // hyp_bias = proj(expmap0(bias)) — replicated per 16-lane group
    float bb = bias[k];
    float b2 = reduce16(bb * bb);
    float bn = fmaxf(sqrtf(b2), MIN_NORM);
    float eb = fast_tanh(bn) * bb / bn;
    float e2 = reduce16(eb * eb);
    float en = fmaxf(sqrtf(e2), MIN_NORM);
    float hb = (en > MAXN) ? eb * (MAXN / en) : eb;
    float y2 = reduce16(hb * hb);

    const long long stride = (long long)gridDim.x * 16;      // rows per sweep
    long long base = ((long long)blockIdx.x * 4 + wib) * 4;  // 4 rows per wave

    // 2-deep prefetch pipeline
    float4 c0 = {0,0,0,0}, c1 = {0,0,0,0};
    float4 n0 = {0,0,0,0}, n1 = {0,0,0,0};
    if (base < N) {
        const float* xr = x + base * 512 + lane * 8;
        c0 = *(const float4*)(xr);
        c1 = *(const float4*)(xr + 4);
    }
    if (base + 1 < N) {
        const float* xr = x + (base + 1) * 512 + lane * 8;
        n0 = *(const float4*)(xr);
        n1 = *(const float4*)(xr + 4);
    }

    while (base < N) {
        float x2sel = 0.0f, mxsel = 0.0f;

#pragma unroll
        for (int p = 0; p < 4; ++p) {
            long long r2 = (p < 2) ? (base + p + 2) : (base + stride + (p - 2));
            float4 m0 = {0,0,0,0}, m1 = {0,0,0,0};
            if (r2 < N) {
                const float* xr = x + r2 * 512 + lane * 8;
                m0 = *(const float4*)(xr);
                m1 = *(const float4*)(xr + 4);
            }

            float xv[8] = {c0.x, c0.y, c0.z, c0.w, c1.x, c1.y, c1.z, c1.w};

            // ||x||^2 over all 64 lanes
            float pq = 0.0f;
#pragma unroll
            for (int jj = 0; jj < 8; ++jj) pq = fmaf(xv[jj], xv[jj], pq);
#pragma unroll
            for (int m = 1; m <= 32; m <<= 1) pq += __shfl_xor(pq, m);
            if (grp == p) x2sel = pq;

            // GEMM + value-halving butterfly
            float v8[8];
            {
                const bool h = lane & 1;
#pragma unroll
                for (int i = 0; i < 8; ++i) {
                    float a0 = 0.0f, a1 = 0.0f;
#pragma unroll
                    for (int jj = 0; jj < 8; ++jj) {
                        a0 = fmaf(wr[2*i][jj],   xv[jj], a0);
                        a1 = fmaf(wr[2*i+1][jj], xv[jj], a1);
                    }
                    float keep = h ? a1 : a0;
                    float give = h ? a0 : a1;
                    v8[i] = keep + __shfl_xor(give, 1);
                }
            }
            float v4[4];
            {
                const bool h = lane & 2;
#pragma unroll
                for (int i = 0; i < 4; ++i) {
                    float keep = h ? v8[2*i+1] : v8[2*i];
                    float give = h ? v8[2*i]   : v8[2*i+1];
                    v4[i] = keep + __shfl_xor(give, 2);
                }
            }
            float v2[2];
            {
                const bool h = lane & 4;
#pragma unroll
                for (int i = 0; i < 2; ++i) {
                    float keep = h ? v4[2*i+1] : v4[2*i];
                    float give = h ? v4[2*i]   : v4[2*i+1];
                    v2[i] = keep + __shfl_xor(give, 4);
                }
            }
            float mx;
            {
                const bool h = lane & 8;
                float keep = h ? v2[1] : v2[0];
                float give = h ? v2[0] : v2[1];
                mx = keep + __shfl_xor(give, 8);
            }
            mx += __shfl_xor(mx, 16);
            mx += __shfl_xor(mx, 32);
            if (grp == p) mxsel = mx;

            c0 = n0; c1 = n1;
            n0 = m0; n1 = m1;
        }

        // ---- Möbius tail: each 16-lane group handles row (base+grp) ----
        float mx2 = reduce16(mxsel * mxsel);
        float xn  = fmaxf(sqrtf(x2sel), MIN_NORM);
        float mxn = fmaxf(sqrtf(mx2),   MIN_NORM);
        float res = fast_tanh(mxn / xn * fast_artanh(xn)) * mxsel / mxn;
        if (mx2 == 0.0f) res = 0.0f;
        float rn2 = reduce16(res * res);
        float rn  = fmaxf(sqrtf(rn2), MIN_NORM);
        float mv  = (rn > MAXN) ? res * (MAXN / rn) : res;
        float mv2 = reduce16(mv * mv);
        float xy  = reduce16(mv * hb);
        float num = (1.0f + 2.0f * xy + y2) * mv + (1.0f - mv2) * hb;
        float den = 1.0f + 2.0f * xy + mv2 * y2;
        float hq  = num / fmaxf(den, MIN_NORM);
        float hn2 = reduce16(hq * hq);
        float hn  = fmaxf(sqrtf(hn2), MIN_NORM);
        float hp  = (hn > MAXN) ? hq * (MAXN / hn) : hq;
        float hp2 = reduce16(hp * hp);
        float pn  = fmaxf(sqrtf(hp2), MIN_NORM);
        float xtv = fast_artanh(pn) * hp / pn;

        long long myrow = base + grp;
        if (myrow < N) xt[myrow * 16 + k] = (_Float16)xtv;

        base += stride;
    }
}

// ---------------- index width detection ----------------
__global__ void hgcn_k_detect(const void* srcp, long long E, int* flag)
{
    const int tid = threadIdx.x;
    if (tid == 0) *flag = 0;
    __syncthreads();
    long long n = E / 2; if (n > 4096) n = 4096;
    int bad = 0;
    const unsigned long long* p = (const unsigned long long*)srcp;
    for (long long i = tid; i < n; i += 256)
        if (p[i] >= (1ULL << 32)) bad = 1;
    if (bad) atomicOr(flag, 1);
}

// ---- kernel 2: edge scatter-add into fp16 agg via packed half2 atomics ----
// 8 lanes/edge, each lane one global_atomic_pk_add_f16 on a 4B pair; 32B
// contiguous per edge. Diagnostic vs fp32-line version: byte-bound -> 2x,
// line-op-rate-bound -> unchanged.
__global__ __launch_bounds__(256) void hgcn_k2(
    const void* __restrict__ srcp, const void* __restrict__ dstp,
    const float* __restrict__ ew, const _Float16* __restrict__ xt,
    __half2* __restrict__ aggh, long long E, const int* __restrict__ flag)
{
    const int sub = threadIdx.x & 7;        // half2 slot 0..7 within row
    const bool i32 = (*flag != 0);
    const long long slots = ((long long)gridDim.x * 256) >> 3;
    long long e = ((long long)blockIdx.x * 256 + threadIdx.x) >> 3;

    long long d0 = 0; float w0 = 0.0f; __half2 v0 = __floats2half2_rn(0.f, 0.f);
    bool have = e < E;
    if (have) {
        long long s0;
        if (i32) { s0 = __builtin_nontemporal_load((const int*)srcp + e);
                   d0 = __builtin_nontemporal_load((const int*)dstp + e); }
        else     { s0 = __builtin_nontemporal_load((const long long*)srcp + e);
                   d0 = __builtin_nontemporal_load((const long long*)dstp + e); }
        w0 = __builtin_nontemporal_load(ew + e);
        v0 = *(const __half2*)(xt + s0 * 16 + sub * 2);
    }
    while (have) {
        long long en = e + slots;
        long long d1 = 0; float w1 = 0.0f; __half2 v1 = __floats2half2_rn(0.f, 0.f);
        bool haven = en < E;
        if (haven) {                      // prefetch next edge
            long long s1;
            if (i32) { s1 = __builtin_nontemporal_load((const int*)srcp + en);
                       d1 = __builtin_nontemporal_load((const int*)dstp + en); }
            else     { s1 = __builtin_nontemporal_load((const long long*)srcp + en);
                       d1 = __builtin_nontemporal_load((const long long*)dstp + en); }
            w1 = __builtin_nontemporal_load(ew + en);
            v1 = *(const __half2*)(xt + s1 * 16 + sub * 2);
        }
        __half2 contrib = __floats2half2_rn(w0 * __low2float(v0),
                                            w0 * __high2float(v0));
        unsafeAtomicAdd(&aggh[d0 * 8 + sub], contrib);   // global_atomic_pk_add_f16
        e = en; d0 = d1; w0 = w1; v0 = v1; have = haven;
    }
}

// ---- kernel 3: finalize — read fp16 agg, full exp/log chain, write fp32 out -
__global__ __launch_bounds__(256) void hgcn_k3(
    const __half* __restrict__ aggh, float* __restrict__ out, int N)
{
    int gid = blockIdx.x * blockDim.x + threadIdx.x;
    int row = gid >> 4;
    if (row >= N) return;
    float u = __half2float(aggh[(size_t)row * 16 + (gid & 15)]);

    float un2 = reduce16(u * u);
    float un  = fmaxf(sqrtf(un2), MIN_NORM);
    float h1  = fast_tanh(un) * u / un;
    float n2  = reduce16(h1 * h1);
    float n1  = fmaxf(sqrtf(n2), MIN_NORM);
    float h1p = (n1 > MAXN) ? h1 * (MAXN / n1) : h1;
    float m2  = reduce16(h1p * h1p);
    float pn  = fmaxf(sqrtf(m2), MIN_NORM);
    float xt2 = fast_artanh(pn) * h1p / pn;
    float a2  = reduce16(xt2 * xt2);
    float an  = fmaxf(sqrtf(a2), MIN_NORM);
    float h2  = fast_tanh(an) * xt2 / an;
    float b2  = reduce16(h2 * h2);
    float bn  = fmaxf(sqrtf(b2), MIN_NORM);
    float h2p = (bn > MAXN) ? h2 * (MAXN / bn) : h2;
    float c2  = reduce16(h2p * h2p);
    float cn  = fmaxf(sqrtf(c2), MIN_NORM);
    out[(size_t)row * 16 + (gid & 15)] = fast_artanh(cn) * h2p / cn;
}

extern "C" void kernel_launch(void* const* d_in, const int* in_sizes, int n_in,
                              void* d_out, int out_size, void* d_ws, size_t ws_size,
                              hipStream_t stream)
{
    const float* x        = (const float*)d_in[0];
    const float* weight   = (const float*)d_in[1];
    const float* bias     = (const float*)d_in[2];
    const float* edge_w   = (const float*)d_in[3];
    const void*  edge_src = d_in[4];
    const void*  edge_dst = d_in[5];

    const int Kv = in_sizes[2];          // 16
    const int Dv = in_sizes[1] / Kv;     // 512
    const int N  = in_sizes[0] / Dv;     // 100000
    const long long E = in_sizes[3];     // 3200000

    // ws layout: [flag 256B][xt fp16 N*16][aggh fp16 N*16] = 256 + 6.4MB
    int*      flag = (int*)d_ws;
    _Float16* xt   = (_Float16*)((char*)d_ws + 256);
    __half2*  aggh = (__half2*)((char*)d_ws + 256 + (size_t)N * 16 * sizeof(_Float16));

    (void)hipMemsetAsync(aggh, 0, (size_t)N * 16 * sizeof(__half), stream);
    hipLaunchKernelGGL(hgcn_k_detect, dim3(1), dim3(256), 0, stream, edge_src, E, flag);
    hipLaunchKernelGGL(hgcn_k1, dim3(1024), dim3(256), 0, stream,
                       x, weight, bias, xt, N);
    hipLaunchKernelGGL(hgcn_k2, dim3(2048), dim3(256), 0, stream,
                       edge_src, edge_dst, edge_w, xt, aggh, E, flag);
    hipLaunchKernelGGL(hgcn_k3, dim3((unsigned)(((long long)N * 16 + 255) / 256)), dim3(256), 0, stream,
                       (const __half*)aggh, (float*)d_out, N);
}